// Round 1
// baseline (207.421 us; speedup 1.0000x reference)
//
#include <hip/hip_runtime.h>
#include <cstdint>
#include <cstddef>

// ---------------------------------------------------------------------------
// SparseConv3DBlock: BN(inference)+SiLU -> gather(27 neighbors) -> implicit GEMM
// N=200000, F_IN=64, F_OUT=128, K=27.
// Strategy: bf16 MFMA (harness threshold 7.09e-2 permits bf16 compute).
//   k1: y_bf16[N][64] = silu(bn(x))                 (ws +0,       25.6 MB)
//   k2: Wt_bf16[27][128][64] = transpose(W)         (ws +25.6MB,  0.44 MB)
//   k3: per 64-voxel block: for k in 0..27: gather A-rows -> LDS (swizzled),
//       B frags from L2-resident Wt, 16x16x32 bf16 MFMA, fp32 out.
// ---------------------------------------------------------------------------

typedef __attribute__((ext_vector_type(8))) short short8;
typedef __attribute__((ext_vector_type(4))) float f32x4;

#define N_VOX 200000
#define F_IN 64
#define F_OUT 128
#define KOFF 27

__device__ __forceinline__ short f2bf(float f) {
  unsigned u = __builtin_bit_cast(unsigned, f);
  u += 0x7fffu + ((u >> 16) & 1u);   // RNE
  return (short)(u >> 16);
}

__device__ __forceinline__ void gload_lds16(const void* g, void* l) {
  __builtin_amdgcn_global_load_lds(
      (const __attribute__((address_space(1))) void*)g,
      (__attribute__((address_space(3))) void*)l, 16, 0, 0);
}

// ---------------- Kernel 1: BN + SiLU + cast to bf16 ----------------------
__global__ __launch_bounds__(256) void bn_silu_kernel(
    const float* __restrict__ x, const float* __restrict__ gamma,
    const float* __restrict__ beta, const float* __restrict__ mean,
    const float* __restrict__ var, short* __restrict__ y) {
  __shared__ float s_scale[F_IN], s_bias[F_IN];
  int tid = threadIdx.x;
  if (tid < F_IN) {
    float s = gamma[tid] * rsqrtf(var[tid] + 1e-5f);
    s_scale[tid] = s;
    s_bias[tid] = beta[tid] - mean[tid] * s;
  }
  __syncthreads();
  size_t i = ((size_t)blockIdx.x * 256 + tid) * 8;   // 12.8M total, exact
  int f0 = (int)(i & (F_IN - 1));                    // multiple of 8
  float4 x0 = *(const float4*)(x + i);
  float4 x1 = *(const float4*)(x + i + 4);
  float v[8] = {x0.x, x0.y, x0.z, x0.w, x1.x, x1.y, x1.z, x1.w};
  short8 o;
#pragma unroll
  for (int j = 0; j < 8; ++j) {
    float t = v[j] * s_scale[f0 + j] + s_bias[f0 + j];
    float sg = 1.0f / (1.0f + __expf(-t));
    o[j] = f2bf(t * sg);
  }
  *(short8*)(y + i) = o;
}

// ---------------- Kernel 2: W[27][64][128] f32 -> Wt[27][128][64] bf16 ----
__global__ __launch_bounds__(256) void wprep_kernel(
    const float* __restrict__ W, short* __restrict__ Wt) {
  int tid = blockIdx.x * 256 + threadIdx.x;        // 27*128*8 = 27648 threads
  if (tid >= KOFF * F_OUT * 8) return;
  int k = tid >> 10;                               // /(128*8)
  int r = tid & 1023;
  int o = r >> 3;
  int f0 = (r & 7) * 8;
  short8 vv;
#pragma unroll
  for (int i = 0; i < 8; ++i)
    vv[i] = f2bf(W[((size_t)k * F_IN + f0 + i) * F_OUT + o]);
  *(short8*)(Wt + ((size_t)k * F_OUT + o) * F_IN + f0) = vv;
}

// ---------------- Kernel 3: gather + implicit GEMM (bf16 MFMA) ------------
// BM=64 voxels/block, 256 threads = 4 waves. Wave w computes rows 0..63 x
// cols [32w, 32w+32): 4 row-tiles x 2 col-tiles of 16x16, K=64 per k-offset.
__global__ __launch_bounds__(256, 4) void conv_mfma_kernel(
    const short* __restrict__ y,     // [N][64] bf16
    const short* __restrict__ Wt,    // [27][128][64] bf16
    const int* __restrict__ nidx,    // [N][27]
    float* __restrict__ out) {       // [N][128] f32
  __shared__ short Atile[64 * 64];   // 8 KB, XOR-swizzled (16B chunk ^= m&7)
  __shared__ int s_idx[64 * KOFF];   // 6.75 KB

  const int tid = threadIdx.x;
  const int wave = tid >> 6;
  const int lane = tid & 63;
  const int lhi = lane >> 4;         // 0..3
  const int llo = lane & 15;
  const int row0 = blockIdx.x * 64;

  // stage this block's neighbor indices (coalesced: contiguous [64][27] ints)
  for (int i = tid; i < 64 * KOFF; i += 256)
    s_idx[i] = nidx[(size_t)row0 * KOFF + i];

  f32x4 acc[4][2] = {};

  for (int k = 0; k < KOFF; ++k) {
    __syncthreads();   // prior iter's A reads done (and s_idx ready on k=0)

    // ---- gather stage: wave w fills rows [16w,16w+16) of Atile ----
    {
      const int c = lane & 7;              // 16B chunk within 128B row
#pragma unroll
      for (int j = 0; j < 2; ++j) {
        int m = wave * 16 + j * 8 + (lane >> 3);   // tile row this lane loads
        int g = s_idx[m * KOFF + k];               // global voxel row
        int cs = c ^ (m & 7);                      // pre-swizzled source chunk
        gload_lds16(y + (size_t)g * F_IN + cs * 8,
                    (char*)Atile + (wave * 16 + j * 8) * 128);
      }
    }

    // ---- B fragments straight from global (Wt is L2-resident, 442 KB) ----
    short8 b[2][2];
#pragma unroll
    for (int ct = 0; ct < 2; ++ct)
#pragma unroll
      for (int kt = 0; kt < 2; ++kt) {
        int col = wave * 32 + ct * 16 + llo;
        int kk = kt * 32 + lhi * 8;
        b[ct][kt] = *(const short8*)(Wt + ((size_t)(k * F_OUT + col)) * F_IN + kk);
      }

    __syncthreads();   // drains vmcnt(0): Atile gathered

    // ---- MFMA: 4 row-tiles x 2 col-tiles x (K=64 -> 2 steps) ----
#pragma unroll
    for (int rt = 0; rt < 4; ++rt) {
      int m = rt * 16 + llo;
      int base = m * 128 + lhi * 16;
      int swz = (m & 7) << 4;
      short8 a0 = *(const short8*)((const char*)Atile + ((base) ^ swz));
      short8 a1 = *(const short8*)((const char*)Atile + ((base + 64) ^ swz));
#pragma unroll
      for (int ct = 0; ct < 2; ++ct) {
        acc[rt][ct] = __builtin_amdgcn_mfma_f32_16x16x32_bf16(
            a0, b[ct][0], acc[rt][ct], 0, 0, 0);
        acc[rt][ct] = __builtin_amdgcn_mfma_f32_16x16x32_bf16(
            a1, b[ct][1], acc[rt][ct], 0, 0, 0);
      }
    }
  }

  // ---- epilogue: C/D layout col=lane&15, row=(lane>>4)*4+j ----
#pragma unroll
  for (int rt = 0; rt < 4; ++rt)
#pragma unroll
    for (int ct = 0; ct < 2; ++ct) {
      int col = wave * 32 + ct * 16 + llo;
#pragma unroll
      for (int j = 0; j < 4; ++j) {
        int row = row0 + rt * 16 + lhi * 4 + j;
        out[(size_t)row * F_OUT + col] = acc[rt][ct][j];
      }
    }
}

// ---------------------------------------------------------------------------
extern "C" void kernel_launch(void* const* d_in, const int* in_sizes, int n_in,
                              void* d_out, int out_size, void* d_ws, size_t ws_size,
                              hipStream_t stream) {
  const float* x     = (const float*)d_in[0];
  const float* gamma = (const float*)d_in[1];
  const float* beta  = (const float*)d_in[2];
  const float* rmean = (const float*)d_in[3];
  const float* rvar  = (const float*)d_in[4];
  const float* W     = (const float*)d_in[5];
  const int*   nidx  = (const int*)d_in[6];
  float* out = (float*)d_out;

  // workspace layout
  short* y_bf16  = (short*)d_ws;                          // 25,600,000 B
  short* Wt_bf16 = (short*)((char*)d_ws + (size_t)N_VOX * F_IN * 2);  // 442,368 B

  // k1: BN+SiLU -> bf16   (200000*64/8 threads = 6250 blocks)
  bn_silu_kernel<<<(N_VOX * F_IN) / (256 * 8), 256, 0, stream>>>(
      x, gamma, beta, rmean, rvar, y_bf16);

  // k2: W transpose -> bf16 (27648 threads = 108 blocks)
  wprep_kernel<<<(KOFF * F_OUT * 8 + 255) / 256, 256, 0, stream>>>(W, Wt_bf16);

  // k3: gather + implicit GEMM, 64 voxels/block -> 3125 blocks
  conv_mfma_kernel<<<N_VOX / 64, 256, 0, stream>>>(y_bf16, Wt_bf16, nidx, out);
}

// Round 2
// 183.740 us; speedup vs baseline: 1.1289x; 1.1289x over previous
//
#include <hip/hip_runtime.h>
#include <cstdint>
#include <cstddef>

// ---------------------------------------------------------------------------
// SparseConv3DBlock: BN(inference)+SiLU -> gather(27 neighbors) -> implicit GEMM
// N=200000, F_IN=64, F_OUT=128, K=27.  bf16 MFMA path.
//   k1: y_bf16[N][64] = silu(bn(x))
//   k2: Wt_bf16[27][128][64] = transpose(W)
//   k3: BM=128 voxels/block, 8 waves. 2-phase pipeline: issue gathers for k+1
//       (global_load_lds, XOR-swizzled source) before MFMA of k; one
//       __syncthreads per iteration drains loads issued a full iter earlier.
// ---------------------------------------------------------------------------

typedef __attribute__((ext_vector_type(8))) short short8;
typedef __attribute__((ext_vector_type(4))) float f32x4;

#define N_VOX 200000
#define F_IN 64
#define F_OUT 128
#define KOFF 27
#define BM 128

__device__ __forceinline__ short f2bf(float f) {
  unsigned u = __builtin_bit_cast(unsigned, f);
  u += 0x7fffu + ((u >> 16) & 1u);   // RNE
  return (short)(u >> 16);
}

__device__ __forceinline__ void gload_lds16(const void* g, void* l) {
  __builtin_amdgcn_global_load_lds(
      (const __attribute__((address_space(1))) void*)g,
      (__attribute__((address_space(3))) void*)l, 16, 0, 0);
}

// ---------------- Kernel 1: BN + SiLU + cast to bf16 ----------------------
__global__ __launch_bounds__(256) void bn_silu_kernel(
    const float* __restrict__ x, const float* __restrict__ gamma,
    const float* __restrict__ beta, const float* __restrict__ mean,
    const float* __restrict__ var, short* __restrict__ y) {
  __shared__ float s_scale[F_IN], s_bias[F_IN];
  int tid = threadIdx.x;
  if (tid < F_IN) {
    float s = gamma[tid] * rsqrtf(var[tid] + 1e-5f);
    s_scale[tid] = s;
    s_bias[tid] = beta[tid] - mean[tid] * s;
  }
  __syncthreads();
  size_t i = ((size_t)blockIdx.x * 256 + tid) * 8;   // 12.8M total, exact
  int f0 = (int)(i & (F_IN - 1));                    // multiple of 8
  float4 x0 = *(const float4*)(x + i);
  float4 x1 = *(const float4*)(x + i + 4);
  float v[8] = {x0.x, x0.y, x0.z, x0.w, x1.x, x1.y, x1.z, x1.w};
  short8 o;
#pragma unroll
  for (int j = 0; j < 8; ++j) {
    float t = v[j] * s_scale[f0 + j] + s_bias[f0 + j];
    float sg = 1.0f / (1.0f + __expf(-t));
    o[j] = f2bf(t * sg);
  }
  *(short8*)(y + i) = o;
}

// ---------------- Kernel 2: W[27][64][128] f32 -> Wt[27][128][64] bf16 ----
__global__ __launch_bounds__(256) void wprep_kernel(
    const float* __restrict__ W, short* __restrict__ Wt) {
  int tid = blockIdx.x * 256 + threadIdx.x;        // 27*128*8 = 27648 threads
  if (tid >= KOFF * F_OUT * 8) return;
  int k = tid >> 10;                               // /(128*8)
  int r = tid & 1023;
  int o = r >> 3;
  int f0 = (r & 7) * 8;
  short8 vv;
#pragma unroll
  for (int i = 0; i < 8; ++i)
    vv[i] = f2bf(W[((size_t)k * F_IN + f0 + i) * F_OUT + o]);
  *(short8*)(Wt + ((size_t)k * F_OUT + o) * F_IN + f0) = vv;
}

// ---------------- Kernel 3: gather + implicit GEMM (bf16 MFMA) ------------
// BM=128 voxels/block, 512 threads = 8 waves. Wave w: rows 0..127 x cols
// [16w,16w+16): 8 row-tiles of 16x16, K=64 per k-offset (16 MFMA/iter).
// 2-phase pipeline over k: issue gathers(k+1) + B(k+1) before MFMA(k).

__global__ __launch_bounds__(512, 4) void conv_mfma_kernel(
    const short* __restrict__ y,     // [N][64] bf16
    const short* __restrict__ Wt,    // [27][128][64] bf16
    const int* __restrict__ nidx,    // [N][27]
    float* __restrict__ out) {       // [N][128] f32
  __shared__ short Atile[2][BM * F_IN];   // 2 x 16 KB, XOR-swizzled chunks
  __shared__ int s_idx[BM * KOFF];        // 13.5 KB

  const int tid = threadIdx.x;
  const int wave = tid >> 6;         // 0..7
  const int lane = tid & 63;
  const int lhi = lane >> 4;         // 0..3
  const int llo = lane & 15;
  const int row0 = blockIdx.x * BM;
  const int nval = (N_VOX - row0 < BM) ? (N_VOX - row0) : BM;

  // stage this block's neighbor indices (coalesced); pad tail rows with 0
  for (int i = tid; i < BM * KOFF; i += 512)
    s_idx[i] = (i < nval * KOFF) ? nidx[(size_t)row0 * KOFF + i] : 0;
  __syncthreads();

  // wave w gathers rows [16w, 16w+16): 2 gload_lds instrs (8 rows each)
  auto issue_gather = [&](int k, int buf) {
    const int c = lane & 7;                     // 16B chunk within 128B row
#pragma unroll
    for (int j = 0; j < 2; ++j) {
      const int m = wave * 16 + j * 8 + (lane >> 3);  // tile row
      const int g = s_idx[m * KOFF + k];              // global voxel row
      const int cs = c ^ (m & 7);                     // pre-swizzled src chunk
      gload_lds16(y + (size_t)g * F_IN + cs * 8,
                  (char*)Atile[buf] + (wave * 16 + j * 8) * (F_IN * 2));
    }
  };

  auto load_b = [&](int k, short8* b) {
    const int col = wave * 16 + llo;
#pragma unroll
    for (int kt = 0; kt < 2; ++kt)
      b[kt] = *(const short8*)(Wt + ((size_t)k * F_OUT + col) * F_IN +
                               kt * 32 + lhi * 8);
  };

  f32x4 acc[8] = {};
  short8 b0[2], b1[2];

  // prologue: stage k=0
  issue_gather(0, 0);
  load_b(0, b0);

#define CONV_BODY(K, BUF, BCUR, BNEXT)                                         \
  {                                                                            \
    __syncthreads(); /* drains vmcnt(0): gathers+B of (K) done, all waves */   \
    if ((K) + 1 < KOFF) {                                                      \
      issue_gather((K) + 1, (BUF) ^ 1);                                        \
      load_b((K) + 1, BNEXT);                                                  \
    }                                                                          \
    _Pragma("unroll")                                                          \
    for (int rt = 0; rt < 8; ++rt) {                                           \
      const int m = rt * 16 + llo;                                             \
      const int base = m * 128 + lhi * 16;                                     \
      const int swz = (m & 7) << 4;                                            \
      short8 a0 = *(const short8*)((const char*)Atile[BUF] + (base ^ swz));    \
      short8 a1 = *(const short8*)((const char*)Atile[BUF] +                   \
                                   ((base + 64) ^ swz));                       \
      acc[rt] = __builtin_amdgcn_mfma_f32_16x16x32_bf16(a0, (BCUR)[0],         \
                                                        acc[rt], 0, 0, 0);     \
      acc[rt] = __builtin_amdgcn_mfma_f32_16x16x32_bf16(a1, (BCUR)[1],         \
                                                        acc[rt], 0, 0, 0);     \
    }                                                                          \
  }

  for (int k = 0; k < 26; k += 2) {
    CONV_BODY(k, 0, b0, b1);
    CONV_BODY(k + 1, 1, b1, b0);
  }
  CONV_BODY(26, 0, b0, b1);
#undef CONV_BODY

  // epilogue: C/D layout col=lane&15, row=(lane>>4)*4+j
#pragma unroll
  for (int rt = 0; rt < 8; ++rt) {
    const int col = wave * 16 + llo;
    const int rbase = row0 + rt * 16 + lhi * 4;
#pragma unroll
    for (int j = 0; j < 4; ++j) {
      const int row = rbase + j;
      if (row < N_VOX) out[(size_t)row * F_OUT + col] = acc[rt][j];
    }
  }
}

// ---------------------------------------------------------------------------
extern "C" void kernel_launch(void* const* d_in, const int* in_sizes, int n_in,
                              void* d_out, int out_size, void* d_ws, size_t ws_size,
                              hipStream_t stream) {
  const float* x     = (const float*)d_in[0];
  const float* gamma = (const float*)d_in[1];
  const float* beta  = (const float*)d_in[2];
  const float* rmean = (const float*)d_in[3];
  const float* rvar  = (const float*)d_in[4];
  const float* W     = (const float*)d_in[5];
  const int*   nidx  = (const int*)d_in[6];
  float* out = (float*)d_out;

  // workspace layout
  short* y_bf16  = (short*)d_ws;                                      // 25.6 MB
  short* Wt_bf16 = (short*)((char*)d_ws + (size_t)N_VOX * F_IN * 2);  // 442 KB

  bn_silu_kernel<<<(N_VOX * F_IN) / (256 * 8), 256, 0, stream>>>(
      x, gamma, beta, rmean, rvar, y_bf16);

  wprep_kernel<<<(KOFF * F_OUT * 8 + 255) / 256, 256, 0, stream>>>(W, Wt_bf16);

  conv_mfma_kernel<<<(N_VOX + BM - 1) / BM, 512, 0, stream>>>(
      y_bf16, Wt_bf16, nidx, out);
}